// Round 10
// baseline (487.525 us; speedup 1.0000x reference)
//
#include <hip/hip_runtime.h>
#include <hip/hip_bf16.h>

// ---------- constants ----------
#define NPATCH 76832   // 32 * 49 * 49
#define NBLK   601     // ceil(NPATCH/128)
#define K1     1280    // 20*8*8

typedef __attribute__((ext_vector_type(8))) short  short8;
typedef __attribute__((ext_vector_type(4))) float  floatx4;

__device__ __forceinline__ unsigned short f2b(float f) {
    unsigned int u = __builtin_bit_cast(unsigned int, f);
    u += 0x7FFFu + ((u >> 16) & 1u);   // RNE
    return (unsigned short)(u >> 16);
}
// HW packed f32x2 -> bf16x2 (v_cvt_pk_bf16_f32), a -> low
__device__ __forceinline__ unsigned int pk2(float a, float b) {
    __hip_bfloat162 h = __float22bfloat162_rn(make_float2(a, b));
    unsigned int u;
    __builtin_memcpy(&u, &h, 4);
    return u;
}

// swizzled chunk index within a 128B pixel-pair window (conv layout)
__device__ __host__ __forceinline__ int swz8(int row, int i) {
    return (((row & 1) * 4 + i) ^ ((row >> 1) & 7));
}

// ---------- single prep kernel: all weight conversions ----------
// sections: W1(327680) W2(65536) W3(65536) W1T(1024) W2T(9216) WfB(8192, linear)
__global__ void prep(const float* __restrict__ f1w, const float* __restrict__ f2w,
                     const float* __restrict__ f3w, const float* __restrict__ c1w,
                     const float* __restrict__ c2w, const float* __restrict__ ffw,
                     unsigned short* __restrict__ W1, unsigned short* __restrict__ W2,
                     unsigned short* __restrict__ W3, unsigned short* __restrict__ W1T,
                     unsigned short* __restrict__ W2T, unsigned short* __restrict__ WfB) {
    int i = blockIdx.x * 256 + threadIdx.x;
    if (i < 327680) { W1[i] = f2b(f1w[i]); return; }
    i -= 327680;
    if (i < 65536) { W2[i] = f2b(f2w[i]); return; }
    i -= 65536;
    if (i < 65536) { W3[i] = f2b(f3w[i]); return; }
    i -= 65536;
    if (i < 1024) {            // W1T[o:32][k:32], conv swizzle
        int o = i >> 5, k = i & 31;
        unsigned short v = 0;
        if (o < 20 && k < 18) v = f2b(c1w[o * 18 + k]);
        W1T[(o >> 1) * 64 + swz8(o, k >> 3) * 8 + (k & 7)] = v;
        return;
    }
    i -= 1024;
    if (i < 9216) {            // W2T[tap][o:32][c:32], conv swizzle
        int tap = i >> 10, rem = i & 1023, o = rem >> 5, c = rem & 31;
        unsigned short v = 0;
        if (o < 20 && c < 20) v = f2b(c2w[o * 180 + c * 9 + tap]);
        W2T[tap * 1024 + (o >> 1) * 64 + swz8(o, c >> 3) * 8 + (c & 7)] = v;
        return;
    }
    i -= 9216;
    if (i < 8192) {            // WfB[o:32][k:256] bf16 LINEAR (o>=27 zero)
        int o = i >> 8, k = i & 255;
        WfB[i] = (o < 27) ? f2b(ffw[o * 256 + k]) : (unsigned short)0;
    }
}

// ---------- fused tile + conv1(MFMA) + conv2(MFMA) (unchanged from R9) ----------
__global__ __launch_bounds__(256, 3) void conv_mfma(
    const float* __restrict__ img,
    const unsigned short* __restrict__ W1T, const float* __restrict__ b1,
    const unsigned short* __restrict__ W2T, const float* __restrict__ b2,
    unsigned short* __restrict__ X, int row0)
{
    __shared__ alignas(16) unsigned short s_buf[8 * 2048 + 64];
    __shared__ alignas(16) unsigned short s_w1t[1024];
    __shared__ alignas(16) unsigned short s_w2t[9216];
    __shared__ float s_b1[32], s_b2[32];
    constexpr int ZOFF = 8 * 2048;

    const int tid = threadIdx.x;
    for (int d = tid; d < 512; d += 256)  ((unsigned int*)s_w1t)[d] = ((const unsigned int*)W1T)[d];
    for (int d = tid; d < 4608; d += 256) ((unsigned int*)s_w2t)[d] = ((const unsigned int*)W2T)[d];
    if (tid < 32) {
        ((unsigned int*)&s_buf[ZOFF])[tid] = 0u;
        s_b1[tid] = (tid < 20) ? b1[tid] : 0.f;
        s_b2[tid] = (tid < 20) ? b2[tid] : 0.f;
    }

    const int q = tid >> 5, t = tid & 31;
    const int Pl = blockIdx.x * 8 + q;
    const int Pi = row0 + Pl;
    const bool valid = Pi < NPATCH;
    int b = 0, hi = 0, wi = 0;
    if (valid) { b = Pi / 2401; int rem = Pi - b * 2401; hi = rem / 49; wi = rem - hi * 49; }
    const int py = t >> 2, px0 = (t & 3) * 2;
    const float* ib = img + (long long)b * 21632 + (hi * 2) * 104 + (wi * 2);

    float win[2][3][4];
    #pragma unroll
    for (int c = 0; c < 2; ++c)
        #pragma unroll
        for (int dy = 0; dy < 3; ++dy) {
            int ny = py + dy - 1;
            int nyc = ny < 0 ? 0 : (ny > 7 ? 7 : ny);
            #pragma unroll
            for (int dxw = 0; dxw < 4; ++dxw) {
                int nx = px0 + dxw - 1;
                int nxc = nx < 0 ? 0 : (nx > 7 ? 7 : nx);
                win[c][dy][dxw] = ib[c * 10816 + nyc * 104 + nxc];
            }
        }

    #pragma unroll
    for (int j = 0; j < 2; ++j) {
        const int px = px0 + j, pl = py * 8 + px;
        float val[18];
        #pragma unroll
        for (int c = 0; c < 2; ++c)
            #pragma unroll
            for (int dy = 0; dy < 3; ++dy) {
                int ny = py + dy - 1;
                bool rok = valid && ((unsigned)ny < 8u);
                #pragma unroll
                for (int dx = 0; dx < 3; ++dx) {
                    int nx = px + dx - 1;
                    bool ok = rok && ((unsigned)nx < 8u);
                    val[c * 9 + dy * 3 + dx] = ok ? win[c][dy][dx + j] : 0.f;
                }
            }
        alignas(16) unsigned int au[16];
        #pragma unroll
        for (int i = 0; i < 9; ++i) au[i] = pk2(val[2 * i], val[2 * i + 1]);
        #pragma unroll
        for (int i = 9; i < 16; ++i) au[i] = 0u;
        unsigned short* base = &s_buf[q * 2048 + (pl >> 1) * 64];
        #pragma unroll
        for (int i = 0; i < 4; ++i)
            *(uint4*)&base[swz8(pl, i) * 8] = ((const uint4*)au)[i];
    }
    __syncthreads();

    const int wave = tid >> 6, lane = tid & 63;
    const int l15 = lane & 15, quad = lane >> 4;
    const int p0 = wave * 2;

    int boffB[2];
    #pragma unroll
    for (int i = 0; i < 2; ++i) {
        int oo = i * 16 + l15;
        boffB[i] = (oo >> 1) * 64 + swz8(oo, quad) * 8;
    }

    short8 a1f[2];
    #pragma unroll
    for (int mt = 0; mt < 2; ++mt) a1f[mt] = *(const short8*)&s_w1t[boffB[mt]];

    floatx4 acc1[2][2][4] = {};
    #pragma unroll
    for (int pp = 0; pp < 2; ++pp)
        #pragma unroll
        for (int nt = 0; nt < 4; ++nt) {
            int pix = nt * 16 + l15;
            short8 pf = *(const short8*)&s_buf[(p0 + pp) * 2048 + (pix >> 1) * 64 + swz8(pix, quad) * 8];
            #pragma unroll
            for (int mt = 0; mt < 2; ++mt)
                acc1[pp][mt][nt] = __builtin_amdgcn_mfma_f32_16x16x32_bf16(a1f[mt], pf, acc1[pp][mt][nt], 0, 0, 0);
        }

    float bv1[2][4];
    #pragma unroll
    for (int mt = 0; mt < 2; ++mt)
        #pragma unroll
        for (int r = 0; r < 4; ++r) bv1[mt][r] = s_b1[mt * 16 + quad * 4 + r];

    #pragma unroll
    for (int pp = 0; pp < 2; ++pp)
        #pragma unroll
        for (int mt = 0; mt < 2; ++mt)
            #pragma unroll
            for (int nt = 0; nt < 4; ++nt) {
                floatx4 v = acc1[pp][mt][nt];
                uint2 w;
                w.x = pk2(fmaxf(v[0] + bv1[mt][0], 0.f), fmaxf(v[1] + bv1[mt][1], 0.f));
                w.y = pk2(fmaxf(v[2] + bv1[mt][2], 0.f), fmaxf(v[3] + bv1[mt][3], 0.f));
                int pix = nt * 16 + l15;
                int off = (p0 + pp) * 2048 + (pix >> 1) * 64
                        + swz8(pix, mt * 2 + (quad >> 1)) * 8 + (quad & 1) * 4;
                *(uint2*)&s_buf[off] = w;
            }

    int syv[4], pxv[4];
    #pragma unroll
    for (int mt = 0; mt < 4; ++mt) { int p = mt * 16 + l15; syv[mt] = p >> 3; pxv[mt] = p & 7; }

    floatx4 acc2[2][4][2] = {};
    #pragma unroll 1
    for (int dy = 0; dy < 3; ++dy) {
        int sy[4]; bool okY[4];
        #pragma unroll
        for (int mt = 0; mt < 4; ++mt) {
            sy[mt] = syv[mt] + dy - 1;
            okY[mt] = (unsigned)sy[mt] < 8u;
        }
        #pragma unroll
        for (int dx = 0; dx < 3; ++dx) {
            const int tap = dy * 3 + dx;
            short8 bf0 = *(const short8*)&s_w2t[tap * 1024 + boffB[0]];
            short8 bf1 = *(const short8*)&s_w2t[tap * 1024 + boffB[1]];
            #pragma unroll
            for (int mt = 0; mt < 4; ++mt) {
                int sx = pxv[mt] + dx - 1;
                bool ok = okY[mt] & ((unsigned)sx < 8u);
                int ps = sy[mt] * 8 + sx;
                int offl = (ps >> 1) * 64 + swz8(ps, quad) * 8;
                #pragma unroll
                for (int pp = 0; pp < 2; ++pp) {
                    int off = ok ? ((p0 + pp) * 2048 + offl) : (ZOFF + quad * 8);
                    short8 af = *(const short8*)&s_buf[off];
                    acc2[pp][mt][0] = __builtin_amdgcn_mfma_f32_16x16x32_bf16(af, bf0, acc2[pp][mt][0], 0, 0, 0);
                    acc2[pp][mt][1] = __builtin_amdgcn_mfma_f32_16x16x32_bf16(af, bf1, acc2[pp][mt][1], 0, 0, 0);
                }
            }
        }
    }

    #pragma unroll
    for (int pp = 0; pp < 2; ++pp) {
        unsigned short* xrow = X + (long long)(blockIdx.x * 8 + p0 + pp) * K1;
        #pragma unroll
        for (int nt = 0; nt < 2; ++nt) {
            const int col = nt * 16 + l15;
            if (col < 20) {
                const float bv = s_b2[col];
                #pragma unroll
                for (int mt = 0; mt < 4; ++mt) {
                    floatx4 v = acc2[pp][mt][nt];
                    uint2 w;
                    w.x = pk2(fmaxf(v[0] + bv, 0.f), fmaxf(v[1] + bv, 0.f));
                    w.y = pk2(fmaxf(v[2] + bv, 0.f), fmaxf(v[3] + bv, 0.f));
                    *(uint2*)&xrow[col * 64 + mt * 16 + quad * 4] = w;
                }
            }
        }
    }
}

// ---------- fc_all v2: barrier-free K-loops, direct global->VGPR fragments ----------
// A = weight rows (wave-exclusive), B = data rows. C[o][row]: o = quad*4+r, row = l15.
// Only h lives in LDS (XOR chunk swizzle pos = (c&~7)|((c&7)^(row&7))).
__global__ __launch_bounds__(256, 3) void fc_all(
    const unsigned short* __restrict__ X,
    const unsigned short* __restrict__ W1, const unsigned short* __restrict__ W2,
    const unsigned short* __restrict__ W3, const unsigned short* __restrict__ WfB,
    const float* __restrict__ b1, const float* __restrict__ b2,
    const float* __restrict__ b3, const float* __restrict__ bf_,
    float* __restrict__ out, int row0)
{
    __shared__ alignas(16) unsigned short s_h[64 * 256];    // 32 KB

    const int tid = threadIdx.x;
    const int m0 = blockIdx.x * 64;
    const int wave = tid >> 6, lane = tid & 63;
    const int l15 = lane & 15, quad = lane >> 4;

    floatx4 acc[4][4];

    // ================= fc1: K=1280, no LDS, no barriers =================
    #pragma unroll
    for (int mt = 0; mt < 4; ++mt)
        #pragma unroll
        for (int nt = 0; nt < 4; ++nt) acc[mt][nt] = floatx4{0.f, 0.f, 0.f, 0.f};

    {
        const unsigned short* wb[4];
        const unsigned short* xb[4];
        #pragma unroll
        for (int mt = 0; mt < 4; ++mt)
            wb[mt] = W1 + (long long)(wave * 64 + mt * 16 + l15) * 1280 + quad * 8;
        #pragma unroll
        for (int nt = 0; nt < 4; ++nt)
            xb[nt] = X + (long long)(m0 + nt * 16 + l15) * 1280 + quad * 8;

        #pragma unroll 2
        for (int k = 0; k < 1280; k += 32) {
            short8 af[4], bf[4];
            #pragma unroll
            for (int mt = 0; mt < 4; ++mt) af[mt] = *(const short8*)(wb[mt] + k);
            #pragma unroll
            for (int nt = 0; nt < 4; ++nt) bf[nt] = *(const short8*)(xb[nt] + k);
            #pragma unroll
            for (int mt = 0; mt < 4; ++mt)
                #pragma unroll
                for (int nt = 0; nt < 4; ++nt)
                    acc[mt][nt] = __builtin_amdgcn_mfma_f32_16x16x32_bf16(af[mt], bf[nt], acc[mt][nt], 0, 0, 0);
        }
    }
    // write h1 = relu(acc + b1)
    #pragma unroll
    for (int mt = 0; mt < 4; ++mt) {
        int obase = wave * 64 + mt * 16 + quad * 4;
        float v0 = b1[obase], v1 = b1[obase + 1], v2 = b1[obase + 2], v3 = b1[obase + 3];
        int clow = mt * 2 + (quad >> 1), sub = (quad & 1) * 4;
        #pragma unroll
        for (int nt = 0; nt < 4; ++nt) {
            int row = nt * 16 + l15;
            int pos = wave * 8 + (clow ^ (row & 7));
            floatx4 v = acc[mt][nt];
            uint2 w;
            w.x = pk2(fmaxf(v[0] + v0, 0.f), fmaxf(v[1] + v1, 0.f));
            w.y = pk2(fmaxf(v[2] + v2, 0.f), fmaxf(v[3] + v3, 0.f));
            *(uint2*)&s_h[row * 256 + pos * 8 + sub] = w;
        }
    }
    __syncthreads();

    // ================= fc2 / fc3: A from global W rows, B from s_h =================
    #pragma unroll 1
    for (int layer = 0; layer < 2; ++layer) {
        const unsigned short* Wp = (layer == 0) ? W2 : W3;
        const float* bp = (layer == 0) ? b2 : b3;

        #pragma unroll
        for (int mt = 0; mt < 4; ++mt)
            #pragma unroll
            for (int nt = 0; nt < 4; ++nt) acc[mt][nt] = floatx4{0.f, 0.f, 0.f, 0.f};

        const unsigned short* wb[4];
        #pragma unroll
        for (int mt = 0; mt < 4; ++mt)
            wb[mt] = Wp + (long long)(wave * 64 + mt * 16 + l15) * 256 + quad * 8;

        #pragma unroll
        for (int it = 0; it < 8; ++it) {     // K windows of 32
            short8 af[4], bf[4];
            #pragma unroll
            for (int mt = 0; mt < 4; ++mt) af[mt] = *(const short8*)(wb[mt] + it * 32);
            int chi = it >> 1, clo4 = (it & 1) * 4 + quad;
            #pragma unroll
            for (int nt = 0; nt < 4; ++nt) {
                int row = nt * 16 + l15;
                bf[nt] = *(const short8*)&s_h[row * 256 + (chi * 8 + (clo4 ^ (row & 7))) * 8];
            }
            #pragma unroll
            for (int mt = 0; mt < 4; ++mt)
                #pragma unroll
                for (int nt = 0; nt < 4; ++nt)
                    acc[mt][nt] = __builtin_amdgcn_mfma_f32_16x16x32_bf16(af[mt], bf[nt], acc[mt][nt], 0, 0, 0);
        }
        __syncthreads();   // all reads of h done before overwrite
        #pragma unroll
        for (int mt = 0; mt < 4; ++mt) {
            int obase = wave * 64 + mt * 16 + quad * 4;
            float v0 = bp[obase], v1 = bp[obase + 1], v2 = bp[obase + 2], v3 = bp[obase + 3];
            int clow = mt * 2 + (quad >> 1), sub = (quad & 1) * 4;
            #pragma unroll
            for (int nt = 0; nt < 4; ++nt) {
                int row = nt * 16 + l15;
                int pos = wave * 8 + (clow ^ (row & 7));
                floatx4 v = acc[mt][nt];
                uint2 w;
                w.x = pk2(fmaxf(v[0] + v0, 0.f), fmaxf(v[1] + v1, 0.f));
                w.y = pk2(fmaxf(v[2] + v2, 0.f), fmaxf(v[3] + v3, 0.f));
                *(uint2*)&s_h[row * 256 + pos * 8 + sub] = w;
            }
        }
        __syncthreads();
    }

    // ================= fcf: A = WfB rows (global, linear), B = h3 rows =================
    floatx4 accf[2] = {};
    const int myrow = wave * 16 + l15;
    #pragma unroll
    for (int w8 = 0; w8 < 8; ++w8) {
        int chi = w8 >> 1, clo = (w8 & 1) * 4 + quad;
        short8 bfr = *(const short8*)&s_h[myrow * 256 + (chi * 8 + (clo ^ (myrow & 7))) * 8];
        #pragma unroll
        for (int mt = 0; mt < 2; ++mt) {
            int o = mt * 16 + l15;
            short8 afr = *(const short8*)(WfB + o * 256 + w8 * 32 + quad * 8);
            accf[mt] = __builtin_amdgcn_mfma_f32_16x16x32_bf16(afr, bfr, accf[mt], 0, 0, 0);
        }
    }
    const int grow = row0 + m0 + myrow;
    if (grow < NPATCH) {
        #pragma unroll
        for (int mt = 0; mt < 2; ++mt) {
            #pragma unroll
            for (int r = 0; r < 4; ++r) {
                int o = mt * 16 + quad * 4 + r;
                if (o < 27)
                    out[(long long)grow * 27 + o] = accf[mt][r] + bf_[o];
            }
        }
    }
}

extern "C" void kernel_launch(void* const* d_in, const int* in_sizes, int n_in,
                              void* d_out, int out_size, void* d_ws, size_t ws_size,
                              hipStream_t stream) {
    const float* images = (const float*)d_in[0];
    const float* c1w = (const float*)d_in[1];
    const float* c1b = (const float*)d_in[2];
    const float* c2w = (const float*)d_in[3];
    const float* c2b = (const float*)d_in[4];
    const float* f1w = (const float*)d_in[5];
    const float* f1b = (const float*)d_in[6];
    const float* f2w = (const float*)d_in[7];
    const float* f2b_ = (const float*)d_in[8];
    const float* f3w = (const float*)d_in[9];
    const float* f3b = (const float*)d_in[10];
    const float* ffw = (const float*)d_in[11];
    const float* ffb = (const float*)d_in[12];

    // ws: [W1][W2][W3][W1T][W2T][WfB][X]
    const long long W1_E = 327680, W2_E = 65536, W3_E = 65536;
    const long long W1T_E = 1024, W2T_E = 9216, WF_E = 8192;
    const long long WB = (W1_E + W2_E + W3_E + W1T_E + W2T_E + WF_E) * 2;  // 954368
    char* ws = (char*)d_ws;
    unsigned short* W1  = (unsigned short*)ws;
    unsigned short* W2  = W1 + W1_E;
    unsigned short* W3  = W2 + W2_E;
    unsigned short* W1T = W3 + W3_E;
    unsigned short* W2T = W1T + W1T_E;
    unsigned short* WfB = W2T + W2T_E;
    unsigned short* X   = (unsigned short*)(ws + WB);

    // per 128-row block: X only = 327680 B
    long long avail = (long long)ws_size - WB - 256;
    int nb_max = (int)(avail / 327680LL);
    if (nb_max < 1) nb_max = 1;
    if (nb_max > NBLK) nb_max = NBLK;
    int nchunks = (NBLK + nb_max - 1) / nb_max;
    int nb_even = (NBLK + nchunks - 1) / nchunks;

    prep<<<1864, 256, 0, stream>>>(f1w, f2w, f3w, c1w, c2w, ffw, W1, W2, W3, W1T, W2T, WfB);

    for (int b0 = 0; b0 < NBLK; b0 += nb_even) {
        int nb = NBLK - b0; if (nb > nb_even) nb = nb_even;
        int row0 = b0 * 128;
        int rows = nb * 128;

        conv_mfma<<<rows / 8, 256, 0, stream>>>(images, W1T, c1b, W2T, c2b, X, row0);
        fc_all<<<rows / 64, 256, 0, stream>>>(X, W1, W2, W3, WfB,
                                              f1b, f2b_, f3b, ffb, (float*)d_out, row0);
    }
}

// Round 11
// 322.481 us; speedup vs baseline: 1.5118x; 1.5118x over previous
//
#include <hip/hip_runtime.h>
#include <hip/hip_bf16.h>

// ---------- constants ----------
#define NPATCH 76832   // 32 * 49 * 49
#define NBLK   601     // ceil(NPATCH/128)
#define K1     1280    // 20*8*8

typedef __attribute__((ext_vector_type(8))) short  short8;
typedef __attribute__((ext_vector_type(4))) float  floatx4;

__device__ __forceinline__ unsigned short f2b(float f) {
    unsigned int u = __builtin_bit_cast(unsigned int, f);
    u += 0x7FFFu + ((u >> 16) & 1u);   // RNE
    return (unsigned short)(u >> 16);
}
// HW packed f32x2 -> bf16x2 (v_cvt_pk_bf16_f32), a -> low
__device__ __forceinline__ unsigned int pk2(float a, float b) {
    __hip_bfloat162 h = __float22bfloat162_rn(make_float2(a, b));
    unsigned int u;
    __builtin_memcpy(&u, &h, 4);
    return u;
}

// async global->LDS, 16B/lane; global addr PER-LANE, lds dest = wave-uniform base + lane*16
__device__ __forceinline__ void gload_lds16(const unsigned short* g, unsigned short* l) {
    __builtin_amdgcn_global_load_lds(
        (__attribute__((address_space(1))) void*)g,
        (__attribute__((address_space(3))) void*)l,
        16, 0, 0);
}

// swizzled chunk index within a 128B pixel-pair window (conv layout)
__device__ __host__ __forceinline__ int swz8(int row, int i) {
    return (((row & 1) * 4 + i) ^ ((row >> 1) & 7));
}

// ---------- prep: weights into MFMA-fragment-coalesced layouts ----------
// F-layout for W[N][K]: element (o,k) -> (khg*16 + wave*4 + mt)*512 + lane*8 + j
//   wave=o>>6, mt=(o>>4)&3, l15=o&15, khg=k>>5, quad=(k>>3)&3, j=k&7, lane=quad*16+l15
// sections: W1F(327680) W2F(65536) W3F(65536) W1T(1024) W2T(9216) WfF(8192)
__global__ void prep(const float* __restrict__ f1w, const float* __restrict__ f2w,
                     const float* __restrict__ f3w, const float* __restrict__ c1w,
                     const float* __restrict__ c2w, const float* __restrict__ ffw,
                     unsigned short* __restrict__ W1F, unsigned short* __restrict__ W2F,
                     unsigned short* __restrict__ W3F, unsigned short* __restrict__ W1T,
                     unsigned short* __restrict__ W2T, unsigned short* __restrict__ WfF) {
    int i = blockIdx.x * 256 + threadIdx.x;
    if (i < 327680) {          // W1F: o in [0,256), k in [0,1280)
        int o = i / 1280, k = i - o * 1280;
        int dst = ((k >> 5) * 16 + (o >> 6) * 4 + ((o >> 4) & 3)) * 512
                + (((k >> 3) & 3) * 16 + (o & 15)) * 8 + (k & 7);
        W1F[dst] = f2b(f1w[i]);
        return;
    }
    i -= 327680;
    if (i < 65536) {           // W2F: o in [0,256), k in [0,256)
        int o = i >> 8, k = i & 255;
        int dst = ((k >> 5) * 16 + (o >> 6) * 4 + ((o >> 4) & 3)) * 512
                + (((k >> 3) & 3) * 16 + (o & 15)) * 8 + (k & 7);
        W2F[dst] = f2b(f2w[i]);
        return;
    }
    i -= 65536;
    if (i < 65536) {           // W3F
        int o = i >> 8, k = i & 255;
        int dst = ((k >> 5) * 16 + (o >> 6) * 4 + ((o >> 4) & 3)) * 512
                + (((k >> 3) & 3) * 16 + (o & 15)) * 8 + (k & 7);
        W3F[dst] = f2b(f3w[i]);
        return;
    }
    i -= 65536;
    if (i < 1024) {            // W1T[o:32][k:32], conv swizzle
        int o = i >> 5, k = i & 31;
        unsigned short v = 0;
        if (o < 20 && k < 18) v = f2b(c1w[o * 18 + k]);
        W1T[(o >> 1) * 64 + swz8(o, k >> 3) * 8 + (k & 7)] = v;
        return;
    }
    i -= 1024;
    if (i < 9216) {            // W2T[tap][o:32][c:32], conv swizzle
        int tap = i >> 10, rem = i & 1023, o = rem >> 5, c = rem & 31;
        unsigned short v = 0;
        if (o < 20 && c < 20) v = f2b(c2w[o * 180 + c * 9 + tap]);
        W2T[tap * 1024 + (o >> 1) * 64 + swz8(o, c >> 3) * 8 + (c & 7)] = v;
        return;
    }
    i -= 9216;
    if (i < 8192) {            // WfF: o in [0,32) (zero-pad >=27), k in [0,256)
        int o = i >> 8, k = i & 255;
        unsigned short v = (o < 27) ? f2b(ffw[o * 256 + k]) : (unsigned short)0;
        int dst = ((k >> 5) * 2 + (o >> 4)) * 512
                + (((k >> 3) & 3) * 16 + (o & 15)) * 8 + (k & 7);
        WfF[dst] = v;
    }
}

// ---------- fused tile + conv1(MFMA) + conv2(MFMA) (unchanged from R9) ----------
__global__ __launch_bounds__(256, 3) void conv_mfma(
    const float* __restrict__ img,
    const unsigned short* __restrict__ W1T, const float* __restrict__ b1,
    const unsigned short* __restrict__ W2T, const float* __restrict__ b2,
    unsigned short* __restrict__ X, int row0)
{
    __shared__ alignas(16) unsigned short s_buf[8 * 2048 + 64];
    __shared__ alignas(16) unsigned short s_w1t[1024];
    __shared__ alignas(16) unsigned short s_w2t[9216];
    __shared__ float s_b1[32], s_b2[32];
    constexpr int ZOFF = 8 * 2048;

    const int tid = threadIdx.x;
    for (int d = tid; d < 512; d += 256)  ((unsigned int*)s_w1t)[d] = ((const unsigned int*)W1T)[d];
    for (int d = tid; d < 4608; d += 256) ((unsigned int*)s_w2t)[d] = ((const unsigned int*)W2T)[d];
    if (tid < 32) {
        ((unsigned int*)&s_buf[ZOFF])[tid] = 0u;
        s_b1[tid] = (tid < 20) ? b1[tid] : 0.f;
        s_b2[tid] = (tid < 20) ? b2[tid] : 0.f;
    }

    const int q = tid >> 5, t = tid & 31;
    const int Pl = blockIdx.x * 8 + q;
    const int Pi = row0 + Pl;
    const bool valid = Pi < NPATCH;
    int b = 0, hi = 0, wi = 0;
    if (valid) { b = Pi / 2401; int rem = Pi - b * 2401; hi = rem / 49; wi = rem - hi * 49; }
    const int py = t >> 2, px0 = (t & 3) * 2;
    const float* ib = img + (long long)b * 21632 + (hi * 2) * 104 + (wi * 2);

    float win[2][3][4];
    #pragma unroll
    for (int c = 0; c < 2; ++c)
        #pragma unroll
        for (int dy = 0; dy < 3; ++dy) {
            int ny = py + dy - 1;
            int nyc = ny < 0 ? 0 : (ny > 7 ? 7 : ny);
            #pragma unroll
            for (int dxw = 0; dxw < 4; ++dxw) {
                int nx = px0 + dxw - 1;
                int nxc = nx < 0 ? 0 : (nx > 7 ? 7 : nx);
                win[c][dy][dxw] = ib[c * 10816 + nyc * 104 + nxc];
            }
        }

    #pragma unroll
    for (int j = 0; j < 2; ++j) {
        const int px = px0 + j, pl = py * 8 + px;
        float val[18];
        #pragma unroll
        for (int c = 0; c < 2; ++c)
            #pragma unroll
            for (int dy = 0; dy < 3; ++dy) {
                int ny = py + dy - 1;
                bool rok = valid && ((unsigned)ny < 8u);
                #pragma unroll
                for (int dx = 0; dx < 3; ++dx) {
                    int nx = px + dx - 1;
                    bool ok = rok && ((unsigned)nx < 8u);
                    val[c * 9 + dy * 3 + dx] = ok ? win[c][dy][dx + j] : 0.f;
                }
            }
        alignas(16) unsigned int au[16];
        #pragma unroll
        for (int i = 0; i < 9; ++i) au[i] = pk2(val[2 * i], val[2 * i + 1]);
        #pragma unroll
        for (int i = 9; i < 16; ++i) au[i] = 0u;
        unsigned short* base = &s_buf[q * 2048 + (pl >> 1) * 64];
        #pragma unroll
        for (int i = 0; i < 4; ++i)
            *(uint4*)&base[swz8(pl, i) * 8] = ((const uint4*)au)[i];
    }
    __syncthreads();

    const int wave = tid >> 6, lane = tid & 63;
    const int l15 = lane & 15, quad = lane >> 4;
    const int p0 = wave * 2;

    int boffB[2];
    #pragma unroll
    for (int i = 0; i < 2; ++i) {
        int oo = i * 16 + l15;
        boffB[i] = (oo >> 1) * 64 + swz8(oo, quad) * 8;
    }

    short8 a1f[2];
    #pragma unroll
    for (int mt = 0; mt < 2; ++mt) a1f[mt] = *(const short8*)&s_w1t[boffB[mt]];

    floatx4 acc1[2][2][4] = {};
    #pragma unroll
    for (int pp = 0; pp < 2; ++pp)
        #pragma unroll
        for (int nt = 0; nt < 4; ++nt) {
            int pix = nt * 16 + l15;
            short8 pf = *(const short8*)&s_buf[(p0 + pp) * 2048 + (pix >> 1) * 64 + swz8(pix, quad) * 8];
            #pragma unroll
            for (int mt = 0; mt < 2; ++mt)
                acc1[pp][mt][nt] = __builtin_amdgcn_mfma_f32_16x16x32_bf16(a1f[mt], pf, acc1[pp][mt][nt], 0, 0, 0);
        }

    float bv1[2][4];
    #pragma unroll
    for (int mt = 0; mt < 2; ++mt)
        #pragma unroll
        for (int r = 0; r < 4; ++r) bv1[mt][r] = s_b1[mt * 16 + quad * 4 + r];

    #pragma unroll
    for (int pp = 0; pp < 2; ++pp)
        #pragma unroll
        for (int mt = 0; mt < 2; ++mt)
            #pragma unroll
            for (int nt = 0; nt < 4; ++nt) {
                floatx4 v = acc1[pp][mt][nt];
                uint2 w;
                w.x = pk2(fmaxf(v[0] + bv1[mt][0], 0.f), fmaxf(v[1] + bv1[mt][1], 0.f));
                w.y = pk2(fmaxf(v[2] + bv1[mt][2], 0.f), fmaxf(v[3] + bv1[mt][3], 0.f));
                int pix = nt * 16 + l15;
                int off = (p0 + pp) * 2048 + (pix >> 1) * 64
                        + swz8(pix, mt * 2 + (quad >> 1)) * 8 + (quad & 1) * 4;
                *(uint2*)&s_buf[off] = w;
            }

    int syv[4], pxv[4];
    #pragma unroll
    for (int mt = 0; mt < 4; ++mt) { int p = mt * 16 + l15; syv[mt] = p >> 3; pxv[mt] = p & 7; }

    floatx4 acc2[2][4][2] = {};
    #pragma unroll 1
    for (int dy = 0; dy < 3; ++dy) {
        int sy[4]; bool okY[4];
        #pragma unroll
        for (int mt = 0; mt < 4; ++mt) {
            sy[mt] = syv[mt] + dy - 1;
            okY[mt] = (unsigned)sy[mt] < 8u;
        }
        #pragma unroll
        for (int dx = 0; dx < 3; ++dx) {
            const int tap = dy * 3 + dx;
            short8 bf0 = *(const short8*)&s_w2t[tap * 1024 + boffB[0]];
            short8 bf1 = *(const short8*)&s_w2t[tap * 1024 + boffB[1]];
            #pragma unroll
            for (int mt = 0; mt < 4; ++mt) {
                int sx = pxv[mt] + dx - 1;
                bool ok = okY[mt] & ((unsigned)sx < 8u);
                int ps = sy[mt] * 8 + sx;
                int offl = (ps >> 1) * 64 + swz8(ps, quad) * 8;
                #pragma unroll
                for (int pp = 0; pp < 2; ++pp) {
                    int off = ok ? ((p0 + pp) * 2048 + offl) : (ZOFF + quad * 8);
                    short8 af = *(const short8*)&s_buf[off];
                    acc2[pp][mt][0] = __builtin_amdgcn_mfma_f32_16x16x32_bf16(af, bf0, acc2[pp][mt][0], 0, 0, 0);
                    acc2[pp][mt][1] = __builtin_amdgcn_mfma_f32_16x16x32_bf16(af, bf1, acc2[pp][mt][1], 0, 0, 0);
                }
            }
        }
    }

    #pragma unroll
    for (int pp = 0; pp < 2; ++pp) {
        unsigned short* xrow = X + (long long)(blockIdx.x * 8 + p0 + pp) * K1;
        #pragma unroll
        for (int nt = 0; nt < 2; ++nt) {
            const int col = nt * 16 + l15;
            if (col < 20) {
                const float bv = s_b2[col];
                #pragma unroll
                for (int mt = 0; mt < 4; ++mt) {
                    floatx4 v = acc2[pp][mt][nt];
                    uint2 w;
                    w.x = pk2(fmaxf(v[0] + bv, 0.f), fmaxf(v[1] + bv, 0.f));
                    w.y = pk2(fmaxf(v[2] + bv, 0.f), fmaxf(v[3] + bv, 0.f));
                    *(uint2*)&xrow[col * 64 + mt * 16 + quad * 4] = w;
                }
            }
        }
    }
}

// ---------- fc_all v3: X staged (XOR-swizzled, BK=128), W direct-coalesced from F-layout ----------
// A = weight rows (F-layout, per-wave), B = data rows. C[o][row]: o = quad*4+r (+mt*16+wave*64), row = l15.
__global__ __launch_bounds__(256, 3) void fc_all(
    const unsigned short* __restrict__ X,
    const unsigned short* __restrict__ W1F, const unsigned short* __restrict__ W2F,
    const unsigned short* __restrict__ W3F, const unsigned short* __restrict__ WfF,
    const float* __restrict__ b1, const float* __restrict__ b2,
    const float* __restrict__ b3, const float* __restrict__ bf_,
    float* __restrict__ out, int row0)
{
    __shared__ alignas(16) unsigned short s_a[64 * 128];    // 16 KB: X tile [row][BK=128], XOR pos
    __shared__ alignas(16) unsigned short s_h[64 * 256];    // 32 KB

    const int tid = threadIdx.x;
    const int m0 = blockIdx.x * 64;
    const int wave = tid >> 6, lane = tid & 63;
    const int l15 = lane & 15, quad = lane >> 4;

    floatx4 acc[4][4];
    #pragma unroll
    for (int mt = 0; mt < 4; ++mt)
        #pragma unroll
        for (int nt = 0; nt < 4; ++nt) acc[mt][nt] = floatx4{0.f, 0.f, 0.f, 0.f};

    // ================= fc1: K=1280, BK=128; only X staging barriers =================
    #pragma unroll 1
    for (int kt = 0; kt < 1280; kt += 128) {
        // stage X: 1024 lane-chunks; g = i*256+tid: row=g>>4, pos=g&15, src chunk cc = (pos&8)|((pos&7)^(row&7))
        #pragma unroll
        for (int i = 0; i < 4; ++i) {
            int g = i * 256 + tid;
            int row = g >> 4, pos = g & 15;
            int cc = (pos & 8) | ((pos & 7) ^ (row & 7));
            gload_lds16(X + (long long)(m0 + row) * 1280 + kt + cc * 8,
                        &s_a[i * 2048 + wave * 512]);
        }
        __syncthreads();
        #pragma unroll
        for (int kh = 0; kh < 4; ++kh) {
            const int khg = (kt >> 5) + kh;
            short8 af[4], bf[4];
            #pragma unroll
            for (int mt = 0; mt < 4; ++mt)
                af[mt] = *(const short8*)(W1F + (khg * 16 + wave * 4 + mt) * 512 + lane * 8);
            #pragma unroll
            for (int nt = 0; nt < 4; ++nt) {
                int row = nt * 16 + l15;
                int c = kh * 4 + quad;
                int pos = (c & 8) | ((c & 7) ^ (row & 7));
                bf[nt] = *(const short8*)&s_a[row * 128 + pos * 8];
            }
            #pragma unroll
            for (int mt = 0; mt < 4; ++mt)
                #pragma unroll
                for (int nt = 0; nt < 4; ++nt)
                    acc[mt][nt] = __builtin_amdgcn_mfma_f32_16x16x32_bf16(af[mt], bf[nt], acc[mt][nt], 0, 0, 0);
        }
        __syncthreads();
    }
    // write h1 = relu(acc + b1) into s_h  (pos = (c&~7)|((c&7)^(row&7)) chunk swizzle)
    #pragma unroll
    for (int mt = 0; mt < 4; ++mt) {
        int obase = wave * 64 + mt * 16 + quad * 4;
        float v0 = b1[obase], v1 = b1[obase + 1], v2 = b1[obase + 2], v3 = b1[obase + 3];
        int clow = mt * 2 + (quad >> 1), sub = (quad & 1) * 4;
        #pragma unroll
        for (int nt = 0; nt < 4; ++nt) {
            int row = nt * 16 + l15;
            int pos = wave * 8 + (clow ^ (row & 7));
            floatx4 v = acc[mt][nt];
            uint2 w;
            w.x = pk2(fmaxf(v[0] + v0, 0.f), fmaxf(v[1] + v1, 0.f));
            w.y = pk2(fmaxf(v[2] + v2, 0.f), fmaxf(v[3] + v3, 0.f));
            *(uint2*)&s_h[row * 256 + pos * 8 + sub] = w;
        }
    }
    __syncthreads();

    // ================= fc2 / fc3: A = W F-layout (global), B = s_h =================
    #pragma unroll 1
    for (int layer = 0; layer < 2; ++layer) {
        const unsigned short* Wp = (layer == 0) ? W2F : W3F;
        const float* bp = (layer == 0) ? b2 : b3;

        #pragma unroll
        for (int mt = 0; mt < 4; ++mt)
            #pragma unroll
            for (int nt = 0; nt < 4; ++nt) acc[mt][nt] = floatx4{0.f, 0.f, 0.f, 0.f};

        #pragma unroll
        for (int it = 0; it < 8; ++it) {
            short8 af[4], bf[4];
            #pragma unroll
            for (int mt = 0; mt < 4; ++mt)
                af[mt] = *(const short8*)(Wp + (it * 16 + wave * 4 + mt) * 512 + lane * 8);
            int chi = it >> 1, clo4 = (it & 1) * 4 + quad;
            #pragma unroll
            for (int nt = 0; nt < 4; ++nt) {
                int row = nt * 16 + l15;
                bf[nt] = *(const short8*)&s_h[row * 256 + (chi * 8 + (clo4 ^ (row & 7))) * 8];
            }
            #pragma unroll
            for (int mt = 0; mt < 4; ++mt)
                #pragma unroll
                for (int nt = 0; nt < 4; ++nt)
                    acc[mt][nt] = __builtin_amdgcn_mfma_f32_16x16x32_bf16(af[mt], bf[nt], acc[mt][nt], 0, 0, 0);
        }
        __syncthreads();   // all reads of h done before overwrite
        #pragma unroll
        for (int mt = 0; mt < 4; ++mt) {
            int obase = wave * 64 + mt * 16 + quad * 4;
            float v0 = bp[obase], v1 = bp[obase + 1], v2 = bp[obase + 2], v3 = bp[obase + 3];
            int clow = mt * 2 + (quad >> 1), sub = (quad & 1) * 4;
            #pragma unroll
            for (int nt = 0; nt < 4; ++nt) {
                int row = nt * 16 + l15;
                int pos = wave * 8 + (clow ^ (row & 7));
                floatx4 v = acc[mt][nt];
                uint2 w;
                w.x = pk2(fmaxf(v[0] + v0, 0.f), fmaxf(v[1] + v1, 0.f));
                w.y = pk2(fmaxf(v[2] + v2, 0.f), fmaxf(v[3] + v3, 0.f));
                *(uint2*)&s_h[row * 256 + pos * 8 + sub] = w;
            }
        }
        __syncthreads();
    }

    // ================= fcf: A = WfF (global, coalesced), B = h3 rows =================
    floatx4 accf[2] = {};
    const int myrow = wave * 16 + l15;
    #pragma unroll
    for (int w8 = 0; w8 < 8; ++w8) {
        int chi = w8 >> 1, clo = (w8 & 1) * 4 + quad;
        short8 bfr = *(const short8*)&s_h[myrow * 256 + (chi * 8 + (clo ^ (myrow & 7))) * 8];
        #pragma unroll
        for (int mt = 0; mt < 2; ++mt) {
            short8 afr = *(const short8*)(WfF + (w8 * 2 + mt) * 512 + lane * 8);
            accf[mt] = __builtin_amdgcn_mfma_f32_16x16x32_bf16(afr, bfr, accf[mt], 0, 0, 0);
        }
    }
    const int grow = row0 + m0 + myrow;
    if (grow < NPATCH) {
        #pragma unroll
        for (int mt = 0; mt < 2; ++mt) {
            #pragma unroll
            for (int r = 0; r < 4; ++r) {
                int o = mt * 16 + quad * 4 + r;
                if (o < 27)
                    out[(long long)grow * 27 + o] = accf[mt][r] + bf_[o];
            }
        }
    }
}

extern "C" void kernel_launch(void* const* d_in, const int* in_sizes, int n_in,
                              void* d_out, int out_size, void* d_ws, size_t ws_size,
                              hipStream_t stream) {
    const float* images = (const float*)d_in[0];
    const float* c1w = (const float*)d_in[1];
    const float* c1b = (const float*)d_in[2];
    const float* c2w = (const float*)d_in[3];
    const float* c2b = (const float*)d_in[4];
    const float* f1w = (const float*)d_in[5];
    const float* f1b = (const float*)d_in[6];
    const float* f2w = (const float*)d_in[7];
    const float* f2b_ = (const float*)d_in[8];
    const float* f3w = (const float*)d_in[9];
    const float* f3b = (const float*)d_in[10];
    const float* ffw = (const float*)d_in[11];
    const float* ffb = (const float*)d_in[12];

    // ws: [W1F][W2F][W3F][W1T][W2T][WfF][X]
    const long long W1_E = 327680, W2_E = 65536, W3_E = 65536;
    const long long W1T_E = 1024, W2T_E = 9216, WF_E = 8192;
    const long long WB = (W1_E + W2_E + W3_E + W1T_E + W2T_E + WF_E) * 2;  // 954368
    char* ws = (char*)d_ws;
    unsigned short* W1F = (unsigned short*)ws;
    unsigned short* W2F = W1F + W1_E;
    unsigned short* W3F = W2F + W2_E;
    unsigned short* W1T = W3F + W3_E;
    unsigned short* W2T = W1T + W1T_E;
    unsigned short* WfF = W2T + W2T_E;
    unsigned short* X   = (unsigned short*)(ws + WB);

    // per 128-row block: X only = 327680 B
    long long avail = (long long)ws_size - WB - 256;
    int nb_max = (int)(avail / 327680LL);
    if (nb_max < 1) nb_max = 1;
    if (nb_max > NBLK) nb_max = NBLK;
    int nchunks = (NBLK + nb_max - 1) / nb_max;
    int nb_even = (NBLK + nchunks - 1) / nchunks;

    prep<<<1864, 256, 0, stream>>>(f1w, f2w, f3w, c1w, c2w, ffw, W1F, W2F, W3F, W1T, W2T, WfF);

    for (int b0 = 0; b0 < NBLK; b0 += nb_even) {
        int nb = NBLK - b0; if (nb > nb_even) nb = nb_even;
        int row0 = b0 * 128;
        int rows = nb * 128;

        conv_mfma<<<rows / 8, 256, 0, stream>>>(images, W1T, c1b, W2T, c2b, X, row0);
        fc_all<<<rows / 64, 256, 0, stream>>>(X, W1F, W2F, W3F, WfF,
                                              f1b, f2b_, f3b, ffb, (float*)d_out, row0);
    }
}